// Round 3
// baseline (357.690 us; speedup 1.0000x reference)
//
#include <hip/hip_runtime.h>

#define HH_EPS 1e-6f

// ws layout (floats): [0..256) = G (16x16), [256..512) = T (16x16 row-major)

// ---------------------------------------------------------------------------
// Full-wave64 sum via DPP (no DS pipe). Result valid in lane 63 only.
// row_shr 1/2/4/8 -> per-16-row sums in lanes 15/31/47/63; row_bcast:15
// (rows 1,3) then row_bcast:31 (rows 2,3) fold rows; lane 63 = total.
// ---------------------------------------------------------------------------
__device__ __forceinline__ float wave_sum64(float x) {
    int v;
    v = __builtin_amdgcn_update_dpp(0, __float_as_int(x), 0x111, 0xf, 0xf, true); x += __int_as_float(v);
    v = __builtin_amdgcn_update_dpp(0, __float_as_int(x), 0x112, 0xf, 0xf, true); x += __int_as_float(v);
    v = __builtin_amdgcn_update_dpp(0, __float_as_int(x), 0x114, 0xf, 0xf, true); x += __int_as_float(v);
    v = __builtin_amdgcn_update_dpp(0, __float_as_int(x), 0x118, 0xf, 0xf, true); x += __int_as_float(v);
    v = __builtin_amdgcn_update_dpp(0, __float_as_int(x), 0x142, 0xa, 0xf, true); x += __int_as_float(v);
    v = __builtin_amdgcn_update_dpp(0, __float_as_int(x), 0x143, 0xc, 0xf, true); x += __int_as_float(v);
    return x;
}

// ---------------------------------------------------------------------------
// K1: Gram matrix. 136 blocks, one per pair (k,i), i<=k.
// ---------------------------------------------------------------------------
__global__ __launch_bounds__(256) void hh_gram(const float* __restrict__ V,
                                               float* __restrict__ ws) {
    int b = blockIdx.x;
    int k = 0;
    while (b >= k + 1) { b -= k + 1; ++k; }
    const int i = b;

    const float4* V4 = (const float4*)V;
    const int t = threadIdx.x;
    const int wave = t >> 6;
    const int lane = t & 63;

    float acc = 0.f;
    #pragma unroll
    for (int c = 0; c < 4; ++c) {
        const float4 a = V4[k * 1024 + t + 256 * c];
        const float4 v = V4[i * 1024 + t + 256 * c];
        acc = fmaf(a.x, v.x, acc);
        acc = fmaf(a.y, v.y, acc);
        acc = fmaf(a.z, v.z, acc);
        acc = fmaf(a.w, v.w, acc);
    }
    acc = wave_sum64(acc);

    __shared__ float red[4];
    if (lane == 63) red[wave] = acc;
    __syncthreads();
    if (t == 0) {
        const float g = red[0] + red[1] + red[2] + red[3];
        ws[k * 16 + i] = g;
        ws[i * 16 + k] = g;
    }
}

// ---------------------------------------------------------------------------
// K2: T factor. One wave; lane j owns column T[.][j] in registers.
// ---------------------------------------------------------------------------
__global__ __launch_bounds__(64) void hh_T(float* __restrict__ ws) {
    __shared__ float Gs[256];
    const int t = threadIdx.x;
    #pragma unroll
    for (int q = 0; q < 4; ++q) Gs[t * 4 + q] = ws[t * 4 + q];
    __syncthreads();

    const int j = t;
    float tc[16];
    #pragma unroll
    for (int k = 0; k < 16; ++k) {
        const float beta = 2.0f / (Gs[k * 16 + k] + HH_EPS);
        float s = 0.f;
        #pragma unroll
        for (int i = 0; i < k; ++i) {
            const float g = Gs[k * 16 + i];
            s = fmaf((i >= j) ? g : 0.f, tc[i], s);
        }
        tc[k] = (j == k) ? beta : ((j < k) ? (-beta * s) : 0.f);
    }
    if (j < 16) {
        #pragma unroll
        for (int i = 0; i < 16; ++i) ws[256 + i * 16 + j] = tc[i];
    }
}

// ---------------------------------------------------------------------------
// K3: fused apply. 4 rows/block, rows in registers (16 float4/thread).
//   y[j][r] = row_r . V[j] ; w = T.y (in-LDS) ; out_r = row_r - sum_j w[j][r]V[j]
// All reductions via DPP (VALU only); one ds_write_b128 per (j) by lane 63.
// ---------------------------------------------------------------------------
__global__ __launch_bounds__(256, 4) void hh_apply(const float* __restrict__ X,
                                                   const float* __restrict__ V,
                                                   const float* __restrict__ ws,
                                                   float* __restrict__ Out) {
    const float4* X4 = (const float4*)X;
    const float4* V4 = (const float4*)V;
    float4* O4 = (float4*)Out;

    const int t = threadIdx.x;
    const int wave = t >> 6;
    const int lane = t & 63;
    const int rb = blockIdx.x * 4;

    __shared__ float Ts[256];                    // T row-major
    __shared__ alignas(16) float pw[16][4][4];   // [j][wave][row]
    __shared__ float yf[16][4];                  // y[j][row]
    __shared__ float wf[16][4];                  // w[k][row]

    // Load 4 rows (coalesced) + T
    float4 xr[4][4];
    #pragma unroll
    for (int r = 0; r < 4; ++r)
        #pragma unroll
        for (int c = 0; c < 4; ++c)
            xr[r][c] = X4[(rb + r) * 1024 + t + 256 * c];
    Ts[t] = ws[256 + t];

    // Phase 1: 16 block-dots of rows against V rows
    #pragma unroll 2
    for (int j = 0; j < 16; ++j) {
        float p0 = 0.f, p1 = 0.f, p2 = 0.f, p3 = 0.f;
        #pragma unroll
        for (int c = 0; c < 4; ++c) {
            const float4 b = V4[j * 1024 + t + 256 * c];
            p0 = fmaf(xr[0][c].x, b.x, p0); p0 = fmaf(xr[0][c].y, b.y, p0);
            p0 = fmaf(xr[0][c].z, b.z, p0); p0 = fmaf(xr[0][c].w, b.w, p0);
            p1 = fmaf(xr[1][c].x, b.x, p1); p1 = fmaf(xr[1][c].y, b.y, p1);
            p1 = fmaf(xr[1][c].z, b.z, p1); p1 = fmaf(xr[1][c].w, b.w, p1);
            p2 = fmaf(xr[2][c].x, b.x, p2); p2 = fmaf(xr[2][c].y, b.y, p2);
            p2 = fmaf(xr[2][c].z, b.z, p2); p2 = fmaf(xr[2][c].w, b.w, p2);
            p3 = fmaf(xr[3][c].x, b.x, p3); p3 = fmaf(xr[3][c].y, b.y, p3);
            p3 = fmaf(xr[3][c].z, b.z, p3); p3 = fmaf(xr[3][c].w, b.w, p3);
        }
        p0 = wave_sum64(p0);
        p1 = wave_sum64(p1);
        p2 = wave_sum64(p2);
        p3 = wave_sum64(p3);
        if (lane == 63)
            *(float4*)&pw[j][wave][0] = make_float4(p0, p1, p2, p3);
    }
    __syncthreads();

    // y[j][r] = sum over waves
    if (t < 64) {
        const int j = t >> 2, r = t & 3;
        yf[j][r] = pw[j][0][r] + pw[j][1][r] + pw[j][2][r] + pw[j][3][r];
    }
    __syncthreads();

    // w = T . y
    if (t < 64) {
        const int k = t >> 2, r = t & 3;
        float s = 0.f;
        #pragma unroll
        for (int j = 0; j < 16; ++j) s = fmaf(Ts[k * 16 + j], yf[j][r], s);
        wf[k][r] = s;
    }
    __syncthreads();

    // Phase 2: out_r = row_r - sum_j w[j][r] * V[j]
    #pragma unroll 2
    for (int j = 0; j < 16; ++j) {
        const float w0 = -wf[j][0], w1 = -wf[j][1];
        const float w2 = -wf[j][2], w3 = -wf[j][3];
        #pragma unroll
        for (int c = 0; c < 4; ++c) {
            const float4 v = V4[j * 1024 + t + 256 * c];
            xr[0][c].x = fmaf(w0, v.x, xr[0][c].x);
            xr[0][c].y = fmaf(w0, v.y, xr[0][c].y);
            xr[0][c].z = fmaf(w0, v.z, xr[0][c].z);
            xr[0][c].w = fmaf(w0, v.w, xr[0][c].w);
            xr[1][c].x = fmaf(w1, v.x, xr[1][c].x);
            xr[1][c].y = fmaf(w1, v.y, xr[1][c].y);
            xr[1][c].z = fmaf(w1, v.z, xr[1][c].z);
            xr[1][c].w = fmaf(w1, v.w, xr[1][c].w);
            xr[2][c].x = fmaf(w2, v.x, xr[2][c].x);
            xr[2][c].y = fmaf(w2, v.y, xr[2][c].y);
            xr[2][c].z = fmaf(w2, v.z, xr[2][c].z);
            xr[2][c].w = fmaf(w2, v.w, xr[2][c].w);
            xr[3][c].x = fmaf(w3, v.x, xr[3][c].x);
            xr[3][c].y = fmaf(w3, v.y, xr[3][c].y);
            xr[3][c].z = fmaf(w3, v.z, xr[3][c].z);
            xr[3][c].w = fmaf(w3, v.w, xr[3][c].w);
        }
    }

    #pragma unroll
    for (int r = 0; r < 4; ++r)
        #pragma unroll
        for (int c = 0; c < 4; ++c)
            O4[(rb + r) * 1024 + t + 256 * c] = xr[r][c];
}

// ---------------------------------------------------------------------------
extern "C" void kernel_launch(void* const* d_in, const int* in_sizes, int n_in,
                              void* d_out, int out_size, void* d_ws, size_t ws_size,
                              hipStream_t stream) {
    const float* X = (const float*)d_in[0];   // (4,2048,4096) f32 = 8192 rows
    const float* V = (const float*)d_in[1];   // (16,4096) f32
    float* O = (float*)d_out;
    float* ws = (float*)d_ws;                 // needs 512 floats

    hh_gram<<<136, 256, 0, stream>>>(V, ws);
    hh_T<<<1, 64, 0, stream>>>(ws);
    hh_apply<<<2048, 256, 0, stream>>>(X, V, ws, O);
}